// Round 23
// baseline (134.544 us; speedup 1.0000x reference)
//
#include <hip/hip_runtime.h>
#include <hip/hip_bf16.h>

typedef __attribute__((ext_vector_type(8))) short short8;
typedef __attribute__((ext_vector_type(4))) float f32x4;
typedef __hip_bfloat16 bf16;

static constexpr int T_TOK = 8192;   // B*S
static constexpr int HD    = 2048;
static constexpr int FD    = 8192;
static constexpr int NE    = 8;

#define MFMA16(a,b,c) __builtin_amdgcn_mfma_f32_16x16x32_bf16((a),(b),(c),0,0,0)

// ---------------- K0: weight convert + pack, zero counts + zero accf ----------------
__global__ __launch_bounds__(256) void k_convert(
    const float* __restrict__ w1A, const float* __restrict__ w1B,
    const float* __restrict__ w2A, const float* __restrict__ w2B,
    const float* __restrict__ w3A, const float* __restrict__ w3B,
    bf16* __restrict__ bw1a3, bf16* __restrict__ bw1b, bf16* __restrict__ bw3b,
    bf16* __restrict__ bw2apk, bf16* __restrict__ bw2b, int* __restrict__ cnt,
    float* __restrict__ accf)
{
  int i = blockIdx.x * 256 + threadIdx.x;          // 0 .. 1048575
  if (blockIdx.x == 0 && threadIdx.x < 16) cnt[threadIdx.x] = 0;
  if (i < T_TOK * 2 * 16) accf[i] = 0.f;           // zero fp32 accumulator (1 MB)
  bw1b[i] = __float2bfloat16(w1B[i]);
  bw3b[i] = __float2bfloat16(w3B[i]);
  { // w2_A [E][R][F] -> A-frag pack for swapped contraction
    int f = i & (FD - 1); int er = i >> 13; int e = er >> 4; int r = er & 15;
    int ft = f >> 5; int fo = f & 31;
    int sub = fo >> 4; int lg = (fo >> 2) & 3; int j = sub * 4 + (fo & 3);
    int lane = lg * 16 + r;
    bw2apk[((e * 256 + ft) * 64 + lane) * 8 + j] = __float2bfloat16(w2A[i]);
  }
  if (i < 256 * HD) { // pack [w1A;w3A] -> [e][kk(64)][rr(32)][kc(32)]
    int h = i & (HD - 1); int nn = i >> 11; int e = nn >> 5; int rr = nn & 31;
    float v = (rr < 16) ? w1A[(e * 16 + rr) * HD + h] : w3A[(e * 16 + (rr - 16)) * HD + h];
    bw1a3[e * 65536 + (h >> 5) * 1024 + rr * 32 + (h & 31)] = __float2bfloat16(v);
  }
  if (i < NE * HD * 16) bw2b[i] = __float2bfloat16(w2B[i]);
}

// ---------------- K1: router (fp32) + gather + selT + bf16-x side product ----------------
// 512 blocks x 512 threads (8 waves); 16 tokens/block, 32 sublanes/token.
__global__ __launch_bounds__(512) void k_router(
    const float* __restrict__ x, const float* __restrict__ gw,
    float* __restrict__ rw_out, int* __restrict__ cnt,
    int* __restrict__ tok, float* __restrict__ wl, int* __restrict__ selT,
    bf16* __restrict__ bx, int use_bx)
{
  int tid = threadIdx.x;
  int j = tid >> 5;            // token within block (0..15)
  int r = tid & 31;            // sublane (0..31)
  int t = blockIdx.x * 16 + j;

  const float4* xr = reinterpret_cast<const float4*>(x + (size_t)t * HD);
  float p[8];
#pragma unroll
  for (int e = 0; e < 8; e++) p[e] = 0.f;
#pragma unroll 4
  for (int it = 0; it < 16; it++) {
    float4 xv = xr[it * 32 + r];
#pragma unroll
    for (int e = 0; e < 8; e++) {
      float4 gv = reinterpret_cast<const float4*>(gw + e * HD)[it * 32 + r];
      p[e] += xv.x * gv.x + xv.y * gv.y + xv.z * gv.z + xv.w * gv.w;
    }
    if (use_bx) {
      alignas(8) bf16 tb[4];
      tb[0] = __float2bfloat16(xv.x); tb[1] = __float2bfloat16(xv.y);
      tb[2] = __float2bfloat16(xv.z); tb[3] = __float2bfloat16(xv.w);
      *reinterpret_cast<uint2*>(bx + (size_t)t * HD + (it * 32 + r) * 4) =
          *reinterpret_cast<const uint2*>(tb);
    }
  }
#pragma unroll
  for (int e = 0; e < 8; e++) {
#pragma unroll
    for (int m = 1; m <= 16; m <<= 1) p[e] += __shfl_xor(p[e], m);
  }

  __shared__ int   se0[16], se1[16];
  __shared__ float sw0[16], sw1[16];
  if (r == 0) {
    float m = -1e30f;
#pragma unroll
    for (int e = 0; e < 8; e++) m = fmaxf(m, p[e]);
    float q[8];
#pragma unroll
    for (int e = 0; e < 8; e++) q[e] = __expf(p[e] - m);
    int i0 = 0; float b0 = q[0];
#pragma unroll
    for (int e = 1; e < 8; e++) if (q[e] > b0) { b0 = q[e]; i0 = e; }
    int i1 = -1; float b1 = -1.f;
#pragma unroll
    for (int e = 0; e < 8; e++) if (e != i0 && q[e] > b1) { b1 = q[e]; i1 = e; }
    float inv = 1.f / (b0 + b1);
    float r0 = b0 * inv, r1 = b1 * inv;
    rw_out[t * 2 + 0] = r0; rw_out[t * 2 + 1] = r1;
    selT[t] = i0 | (i1 << 8);
    se0[j] = i0; se1[j] = i1; sw0[j] = r0; sw1[j] = r1;
  }
  __syncthreads();
  if (tid < 16) {
    int ls = tid, e = ls >> 1, slot = ls & 1;
    int c = 0;
#pragma unroll
    for (int jj = 0; jj < 16; jj++)
      c += (slot == 0 ? (se0[jj] == e) : (se1[jj] == e)) ? 1 : 0;
    if (c > 0) {
      int base = atomicAdd(&cnt[ls], c);
      int k = 0;
#pragma unroll
      for (int jj = 0; jj < 16; jj++) {
        bool hit = (slot == 0 ? (se0[jj] == e) : (se1[jj] == e));
        if (hit) {
          tok[ls * T_TOK + base + k] = blockIdx.x * 16 + jj;
          wl [ls * T_TOK + base + k] = (slot == 0 ? sw0[jj] : sw1[jj]);
          k++;
        }
      }
    }
  }
}

// ---------------- K3: fused gathered stage1 (Phase A) + F-half-loop (Phase B) ----------
// PBLK=32, 512 threads / 8 waves. F split across 2 blocks per (ls,pt): item =
// (pt<<5)|(fhalf<<4)|lsbits -> 1024 live blocks (4/CU, 32 waves/CU). Per-wave
// Phase-B iteration structure identical to the 66.5us config (intensity preserved);
// the two F-half partials combine via fp32 atomicAdd (2 addends -> commutative,
// bitwise deterministic). Phase A duplicated per fhalf (cheap, ~25%).
#define LDW(FT, B1, B3, W2) { \
    int f0_ = fbase + (FT) * 32; \
    _Pragma("unroll") \
    for (int sub = 0; sub < 2; sub++) { \
      int f_ = f0_ + sub * 16 + lm; \
      B1[sub] = *reinterpret_cast<const short8*>(w1e + f_ * 16 + r8); \
      B3[sub] = *reinterpret_cast<const short8*>(w3e + f_ * 16 + r8); \
    } \
    W2 = *reinterpret_cast<const short8*>(w2e + ((size_t)(f0_ >> 5) * 64 + l) * 8); }

#define CMP(B1, B3, W2) \
  _Pragma("unroll") \
  for (int m = 0; m < 2; m++) { \
    short8 hfrag; \
    _Pragma("unroll") \
    for (int sub = 0; sub < 2; sub++) { \
      f32x4 h1 = MFMA16(B1[sub], A1[m], zf); \
      f32x4 h3 = MFMA16(B3[sub], A3[m], zf); \
      _Pragma("unroll") \
      for (int i = 0; i < 4; i++) { \
        float a = h1[i]; \
        float hv = (a >= 0.f ? a : 0.01f * a) * h3[i]; \
        bf16 hb = __float2bfloat16(hv); \
        hfrag[sub * 4 + i] = *reinterpret_cast<short*>(&hb); \
      } \
    } \
    acc[m] = MFMA16(W2, hfrag, acc[m]); }

__global__ __launch_bounds__(512) void k_fused(
    const float* __restrict__ x, const bf16* __restrict__ bx, int use_bx,
    const bf16* __restrict__ bw1a3,
    const bf16* __restrict__ bw1b, const bf16* __restrict__ bw3b,
    const bf16* __restrict__ bw2apk,
    const int* __restrict__ cnt, const int* __restrict__ tok,
    const float* __restrict__ wl, float* __restrict__ accf)
{
  int item = blockIdx.x;
  int ls = ((item & 7) << 1) | ((item >> 3) & 1);   // expert = XCD (b%8)
  int fhalf = (item >> 4) & 1;                      // F-half 0/1
  int pt = item >> 5;                               // 0..255
  int n = cnt[ls]; int p0 = pt * 32;
  if (p0 >= n) return;
  int e = ls >> 1;
  int tid = threadIdx.x;
  int w = tid >> 6, l = tid & 63, lm = l & 15, lg = l >> 4;

  __shared__ int toks[32];
  __shared__ __align__(16) bf16 aT[32 * 40];                 // 2.5 KB a1a3 tile
  __shared__ __align__(16) char uni[4352 * 4];               // 17.4 KB union
  float* part = reinterpret_cast<float*>(uni);               // [4][32][33] Phase A
  float* red  = reinterpret_cast<float*>(uni);               // [8][32*17]  Phase B

  const f32x4 zf = {0.f, 0.f, 0.f, 0.f};
  const short8 ZS = {0, 0, 0, 0, 0, 0, 0, 0};

  if (tid < 32) {
    int pos = p0 + tid; if (pos > n - 1) pos = n - 1;
    toks[tid] = tok[ls * T_TOK + pos];
  }
  __syncthreads();

  // ---- Phase A: gathered stage-1, one expert, ILP-4 ----
  {
    int tg = w >> 2, ks = w & 3;            // token-group (2), K-slice (4 x 512)
    const bf16* be = bw1a3 + e * 65536 + ks * 16384 + lg * 8;
    f32x4 a0 = zf, a1 = zf, a2 = zf, a3 = zf;
    if (use_bx) {
      const bf16* xp = bx + (size_t)toks[tg * 16 + lm] * HD + ks * 512 + lg * 8;
#pragma unroll 4
      for (int k2 = 0; k2 < 8; k2++) {
        short8 af0 = *reinterpret_cast<const short8*>(xp + (2 * k2) * 32);
        short8 af1 = *reinterpret_cast<const short8*>(xp + (2 * k2 + 1) * 32);
        short8 b00 = *reinterpret_cast<const short8*>(be + (2 * k2) * 1024 + lm * 32);
        short8 b01 = *reinterpret_cast<const short8*>(be + (2 * k2) * 1024 + (lm + 16) * 32);
        short8 b10 = *reinterpret_cast<const short8*>(be + (2 * k2 + 1) * 1024 + lm * 32);
        short8 b11 = *reinterpret_cast<const short8*>(be + (2 * k2 + 1) * 1024 + (lm + 16) * 32);
        a0 = MFMA16(af0, b00, a0);
        a1 = MFMA16(af0, b01, a1);
        a2 = MFMA16(af1, b10, a2);
        a3 = MFMA16(af1, b11, a3);
      }
    } else {
      const float* xp = x + (size_t)toks[tg * 16 + lm] * HD + ks * 512 + lg * 8;
#pragma unroll 4
      for (int kk2 = 0; kk2 < 16; kk2++) {
        float4 v0 = *reinterpret_cast<const float4*>(xp + kk2 * 32);
        float4 v1 = *reinterpret_cast<const float4*>(xp + kk2 * 32 + 4);
        alignas(16) bf16 tmp[8];
        tmp[0] = __float2bfloat16(v0.x); tmp[1] = __float2bfloat16(v0.y);
        tmp[2] = __float2bfloat16(v0.z); tmp[3] = __float2bfloat16(v0.w);
        tmp[4] = __float2bfloat16(v1.x); tmp[5] = __float2bfloat16(v1.y);
        tmp[6] = __float2bfloat16(v1.z); tmp[7] = __float2bfloat16(v1.w);
        short8 af = *reinterpret_cast<const short8*>(tmp);
        short8 b0 = *reinterpret_cast<const short8*>(be + kk2 * 1024 + lm * 32);
        short8 b1 = *reinterpret_cast<const short8*>(be + kk2 * 1024 + (lm + 16) * 32);
        a0 = MFMA16(af, b0, a0);
        a1 = MFMA16(af, b1, a1);
      }
    }
    a0 += a2; a1 += a3;
    // C: col=lm (rr), row(token-in-group)=lg*4+i
#pragma unroll
    for (int i = 0; i < 4; i++) {
      int row = tg * 16 + lg * 4 + i;
      part[(ks * 32 + row) * 33 + lm]      = a0[i];
      part[(ks * 32 + row) * 33 + 16 + lm] = a1[i];
    }
  }
  __syncthreads();
  { // reduce 4 K-slices -> aT (bf16); 512 threads x 2 elems
    int tokr = tid >> 4, c2 = (tid & 15) * 2;
    float s0 = 0.f, s1 = 0.f;
#pragma unroll
    for (int ks = 0; ks < 4; ks++) {
      s0 += part[(ks * 32 + tokr) * 33 + c2];
      s1 += part[(ks * 32 + tokr) * 33 + c2 + 1];
    }
    aT[tokr * 40 + c2]     = __float2bfloat16(s0);
    aT[tokr * 40 + c2 + 1] = __float2bfloat16(s1);
  }
  __syncthreads();

  // ---- Phase B: F-loop, wave w owns 512-wide slice of this block's F-half ----
  short8 A1[2], A3[2];
#pragma unroll
  for (int m = 0; m < 2; m++) {
    if (lg < 2) {
      A1[m] = *reinterpret_cast<const short8*>(&aT[(m * 16 + lm) * 40 + lg * 8]);
      A3[m] = *reinterpret_cast<const short8*>(&aT[(m * 16 + lm) * 40 + 16 + lg * 8]);
    } else { A1[m] = ZS; A3[m] = ZS; }
  }
  f32x4 acc[2];
  acc[0] = zf; acc[1] = zf;
  int r8 = (lg & 1) * 8;
  int fbase = fhalf * 4096 + w * 512;
  const bf16* w1e = bw1b   + (size_t)e * FD * 16;
  const bf16* w3e = bw3b   + (size_t)e * FD * 16;
  const bf16* w2e = bw2apk + (size_t)e * 131072;

  short8 b1A[2], b3A[2], w2A_;
  short8 b1B[2], b3B[2], w2B_;
  LDW(0, b1A, b3A, w2A_);
  for (int ft = 0; ft < 16; ft += 2) {
    LDW(ft + 1, b1B, b3B, w2B_);
    CMP(b1A, b3A, w2A_);
    if (ft + 2 < 16) { LDW(ft + 2, b1A, b3A, w2A_); }
    CMP(b1B, b3B, w2B_);
  }
  // acc[m]: lane holds r = lg*4+i, pair = m*16+lm
#pragma unroll
  for (int m = 0; m < 2; m++)
#pragma unroll
    for (int i = 0; i < 4; i++)
      red[w * 544 + (m * 16 + lm) * 17 + lg * 4 + i] = acc[m][i];
  __syncthreads();
  {
    int p = tid >> 4, rh = tid & 15;       // 32 pairs x 16 r-columns
    int pos = p0 + p;
    if (pos < n) {
      float s = 0.f;
#pragma unroll
      for (int ww = 0; ww < 8; ww++) s += red[ww * 544 + p * 17 + rh];
      float wgt = wl[ls * T_TOK + pos];
      int t = toks[p];
      int sl = ls & 1;
      atomicAdd(&accf[((size_t)t * 2 + sl) * 16 + rh], s * wgt);
    }
  }
}

// ---------------- K4: single-pass dense out: y = acc0@w2B[e0]^T + acc1@w2B[e1]^T -------
// grid: tpt(128) x ht(16); block = 64 tokens x 128 cols; slot0 in K<16, slot1 in K>=16.
// A-fragment loaded from fp32 accf and converted to bf16.
__global__ __launch_bounds__(256) void k_out(
    const float* __restrict__ accf, const bf16* __restrict__ bw2b,
    const int* __restrict__ selT, float* __restrict__ out)
{
  int tpt = blockIdx.x >> 4;
  int ht  = blockIdx.x & 15;
  int tid = threadIdx.x, w = tid >> 6, l = tid & 63, lm = l & 15, lg = l >> 4;
  int t0 = tpt * 64;
  int tA = t0 + w * 16 + lm;                 // token carried by this lane's A rows
  int r8 = (lg & 1) * 8;
  int slot = lg >> 1;                        // lg 0,1 -> slot0 (k<16); lg 2,3 -> slot1
  const float* ap = accf + ((size_t)tA * 2 + slot) * 16 + r8;
  float4 av0 = *reinterpret_cast<const float4*>(ap);
  float4 av1 = *reinterpret_cast<const float4*>(ap + 4);
  alignas(16) bf16 atmp[8];
  atmp[0] = __float2bfloat16(av0.x); atmp[1] = __float2bfloat16(av0.y);
  atmp[2] = __float2bfloat16(av0.z); atmp[3] = __float2bfloat16(av0.w);
  atmp[4] = __float2bfloat16(av1.x); atmp[5] = __float2bfloat16(av1.y);
  atmp[6] = __float2bfloat16(av1.z); atmp[7] = __float2bfloat16(av1.w);
  short8 A = *reinterpret_cast<const short8*>(atmp);
  int sel = selT[tA];
  int my_e = (slot == 0) ? (sel & 255) : (sel >> 8);

  const short8 ZS = {0, 0, 0, 0, 0, 0, 0, 0};
  const f32x4 zf = {0.f, 0.f, 0.f, 0.f};
  f32x4 y[2][4];
#pragma unroll
  for (int nt = 0; nt < 2; nt++)
#pragma unroll
    for (int hi = 0; hi < 4; hi++) y[nt][hi] = zf;

#pragma unroll
  for (int e = 0; e < 8; e++) {
    short8 Ae = (my_e == e) ? A : ZS;        // per-lane mask
    const bf16* wbe = bw2b + (size_t)e * HD * 16;
#pragma unroll
    for (int nt = 0; nt < 2; nt++) {
#pragma unroll
      for (int hi = 0; hi < 4; hi++) {
        int h = ht * 128 + nt * 64 + hi * 16 + lm;
        short8 B = *reinterpret_cast<const short8*>(wbe + h * 16 + r8);
        y[nt][hi] = MFMA16(Ae, B, y[nt][hi]);
      }
    }
  }
  // D: row = lg*4+i (token), col = lm (h)
#pragma unroll
  for (int nt = 0; nt < 2; nt++)
#pragma unroll
    for (int hi = 0; hi < 4; hi++)
#pragma unroll
      for (int i = 0; i < 4; i++)
        out[(size_t)(t0 + w * 16 + lg * 4 + i) * HD + ht * 128 + nt * 64 + hi * 16 + lm]
            = y[nt][hi][i];
}

// ---------------- launch ----------------
extern "C" void kernel_launch(void* const* d_in, const int* in_sizes, int n_in,
                              void* d_out, int out_size, void* d_ws, size_t ws_size,
                              hipStream_t stream)
{
  const float* x   = (const float*)d_in[0];
  const float* gw  = (const float*)d_in[1];
  const float* w1A = (const float*)d_in[2];
  const float* w1B = (const float*)d_in[3];
  const float* w2A = (const float*)d_in[4];
  const float* w2B = (const float*)d_in[5];
  const float* w3A = (const float*)d_in[6];
  const float* w3B = (const float*)d_in[7];
  float* out = (float*)d_out;
  float* rw  = out + (size_t)T_TOK * HD;

  char* ws = (char*)d_ws;
  bf16*  bw1a3  = (bf16*)(ws + 0);          //  1 MiB   packed [E][64][32][32]
  bf16*  bw1b   = (bf16*)(ws + 1048576);    //  2 MiB   [E][F][R]
  bf16*  bw3b   = (bf16*)(ws + 3145728);    //  2 MiB
  bf16*  bw2apk = (bf16*)(ws + 5242880);    //  2 MiB   A-frag packed [E][256][64][8]
  bf16*  bw2b   = (bf16*)(ws + 7340032);    //  0.5 MiB [E][H][R]
  float* accf   = (float*)(ws + 8388608);   //  1 MiB   fp32 [T][2][16] accumulator
  int*   cnt    = (int*) (ws + 16777216);   //  64 B (padded)
  int*   tok    = (int*) (ws + 16777472);   //  0.5 MiB [16][T]
  float* wl     = (float*)(ws + 17301760);  //  0.5 MiB [16][T]
  int*   selT   = (int*) (ws + 17825792);   //  32 KiB  [T]
  bf16*  bx     = (bf16*)(ws + 18874368);   //  32 MiB  [T][H] bf16 x (optional)
  int use_bx = (ws_size >= (size_t)18874368 + 33554432) ? 1 : 0;

  k_convert<<<dim3(4096), dim3(256), 0, stream>>>(w1A, w1B, w2A, w2B, w3A, w3B,
                                                  bw1a3, bw1b, bw3b, bw2apk, bw2b, cnt, accf);
  k_router <<<dim3(512),  dim3(512), 0, stream>>>(x, gw, rw, cnt, tok, wl, selT, bx, use_bx);
  k_fused  <<<dim3(8192), dim3(512), 0, stream>>>(x, bx, use_bx, bw1a3, bw1b, bw3b, bw2apk,
                                                  cnt, tok, wl, accf);
  k_out    <<<dim3(2048), dim3(256), 0, stream>>>(accf, bw2b, selT, out);
}

// Round 24
// 126.097 us; speedup vs baseline: 1.0670x; 1.0670x over previous
//
#include <hip/hip_runtime.h>
#include <hip/hip_bf16.h>

typedef __attribute__((ext_vector_type(8))) short short8;
typedef __attribute__((ext_vector_type(4))) float f32x4;
typedef __hip_bfloat16 bf16;

static constexpr int T_TOK = 8192;   // B*S
static constexpr int HD    = 2048;
static constexpr int FD    = 8192;
static constexpr int NE    = 8;

#define MFMA16(a,b,c) __builtin_amdgcn_mfma_f32_16x16x32_bf16((a),(b),(c),0,0,0)

// ---------------- K0: weight convert + pack, zero counts ----------------
__global__ __launch_bounds__(256) void k_convert(
    const float* __restrict__ w1A, const float* __restrict__ w1B,
    const float* __restrict__ w2A, const float* __restrict__ w2B,
    const float* __restrict__ w3A, const float* __restrict__ w3B,
    bf16* __restrict__ bw1a3, bf16* __restrict__ bw1b, bf16* __restrict__ bw3b,
    bf16* __restrict__ bw2apk, bf16* __restrict__ bw2b, int* __restrict__ cnt)
{
  int i = blockIdx.x * 256 + threadIdx.x;          // 0 .. 1048575
  if (blockIdx.x == 0 && threadIdx.x < 16) cnt[threadIdx.x] = 0;
  bw1b[i] = __float2bfloat16(w1B[i]);
  bw3b[i] = __float2bfloat16(w3B[i]);
  { // w2_A [E][R][F] -> A-frag pack for swapped contraction
    int f = i & (FD - 1); int er = i >> 13; int e = er >> 4; int r = er & 15;
    int ft = f >> 5; int fo = f & 31;
    int sub = fo >> 4; int lg = (fo >> 2) & 3; int j = sub * 4 + (fo & 3);
    int lane = lg * 16 + r;
    bw2apk[((e * 256 + ft) * 64 + lane) * 8 + j] = __float2bfloat16(w2A[i]);
  }
  if (i < 256 * HD) { // pack [w1A;w3A] -> [e][kk(64)][rr(32)][kc(32)]
    int h = i & (HD - 1); int nn = i >> 11; int e = nn >> 5; int rr = nn & 31;
    float v = (rr < 16) ? w1A[(e * 16 + rr) * HD + h] : w3A[(e * 16 + (rr - 16)) * HD + h];
    bw1a3[e * 65536 + (h >> 5) * 1024 + rr * 32 + (h & 31)] = __float2bfloat16(v);
  }
  if (i < NE * HD * 16) bw2b[i] = __float2bfloat16(w2B[i]);
}

// ---------------- K1: router (fp32) + gather + selT + bf16-x side product ----------------
// 512 blocks x 512 threads (8 waves); 16 tokens/block, 32 sublanes/token.
__global__ __launch_bounds__(512) void k_router(
    const float* __restrict__ x, const float* __restrict__ gw,
    float* __restrict__ rw_out, int* __restrict__ cnt,
    int* __restrict__ tok, float* __restrict__ wl, int* __restrict__ selT,
    bf16* __restrict__ bx, int use_bx)
{
  int tid = threadIdx.x;
  int j = tid >> 5;            // token within block (0..15)
  int r = tid & 31;            // sublane (0..31)
  int t = blockIdx.x * 16 + j;

  const float4* xr = reinterpret_cast<const float4*>(x + (size_t)t * HD);
  float p[8];
#pragma unroll
  for (int e = 0; e < 8; e++) p[e] = 0.f;
#pragma unroll 4
  for (int it = 0; it < 16; it++) {
    float4 xv = xr[it * 32 + r];
#pragma unroll
    for (int e = 0; e < 8; e++) {
      float4 gv = reinterpret_cast<const float4*>(gw + e * HD)[it * 32 + r];
      p[e] += xv.x * gv.x + xv.y * gv.y + xv.z * gv.z + xv.w * gv.w;
    }
    if (use_bx) {
      alignas(8) bf16 tb[4];
      tb[0] = __float2bfloat16(xv.x); tb[1] = __float2bfloat16(xv.y);
      tb[2] = __float2bfloat16(xv.z); tb[3] = __float2bfloat16(xv.w);
      *reinterpret_cast<uint2*>(bx + (size_t)t * HD + (it * 32 + r) * 4) =
          *reinterpret_cast<const uint2*>(tb);
    }
  }
#pragma unroll
  for (int e = 0; e < 8; e++) {
#pragma unroll
    for (int m = 1; m <= 16; m <<= 1) p[e] += __shfl_xor(p[e], m);
  }

  __shared__ int   se0[16], se1[16];
  __shared__ float sw0[16], sw1[16];
  if (r == 0) {
    float m = -1e30f;
#pragma unroll
    for (int e = 0; e < 8; e++) m = fmaxf(m, p[e]);
    float q[8];
#pragma unroll
    for (int e = 0; e < 8; e++) q[e] = __expf(p[e] - m);
    int i0 = 0; float b0 = q[0];
#pragma unroll
    for (int e = 1; e < 8; e++) if (q[e] > b0) { b0 = q[e]; i0 = e; }
    int i1 = -1; float b1 = -1.f;
#pragma unroll
    for (int e = 0; e < 8; e++) if (e != i0 && q[e] > b1) { b1 = q[e]; i1 = e; }
    float inv = 1.f / (b0 + b1);
    float r0 = b0 * inv, r1 = b1 * inv;
    rw_out[t * 2 + 0] = r0; rw_out[t * 2 + 1] = r1;
    selT[t] = i0 | (i1 << 8);
    se0[j] = i0; se1[j] = i1; sw0[j] = r0; sw1[j] = r1;
  }
  __syncthreads();
  if (tid < 16) {
    int ls = tid, e = ls >> 1, slot = ls & 1;
    int c = 0;
#pragma unroll
    for (int jj = 0; jj < 16; jj++)
      c += (slot == 0 ? (se0[jj] == e) : (se1[jj] == e)) ? 1 : 0;
    if (c > 0) {
      int base = atomicAdd(&cnt[ls], c);
      int k = 0;
#pragma unroll
      for (int jj = 0; jj < 16; jj++) {
        bool hit = (slot == 0 ? (se0[jj] == e) : (se1[jj] == e));
        if (hit) {
          tok[ls * T_TOK + base + k] = blockIdx.x * 16 + jj;
          wl [ls * T_TOK + base + k] = (slot == 0 ? sw0[jj] : sw1[jj]);
          k++;
        }
      }
    }
  }
}

// ---------------- K3: fused gathered stage1 (Phase A) + F-loop (Phase B) ----------------
// PBLK=32 (measured best: 32->66.5us vs 16->76us vs 64->97us; F-split R23: 75us). 512
// threads / 8 waves; grid = 4096 items (~512 live). Phase A: 2 tok-groups x 4 K-slices,
// ILP-4. Phase B: wave w F-slice 1024, 2 m-groups. No setprio (R20: -6us), no NT stores
// (R21: -3us), no F-split (R23: -8.5us). This is the converged optimum of this structure.
#define LDW(FT, B1, B3, W2) { \
    int f0_ = w * 1024 + (FT) * 32; \
    _Pragma("unroll") \
    for (int sub = 0; sub < 2; sub++) { \
      int f_ = f0_ + sub * 16 + lm; \
      B1[sub] = *reinterpret_cast<const short8*>(w1e + f_ * 16 + r8); \
      B3[sub] = *reinterpret_cast<const short8*>(w3e + f_ * 16 + r8); \
    } \
    W2 = *reinterpret_cast<const short8*>(w2e + ((size_t)(f0_ >> 5) * 64 + l) * 8); }

#define CMP(B1, B3, W2) \
  _Pragma("unroll") \
  for (int m = 0; m < 2; m++) { \
    short8 hfrag; \
    _Pragma("unroll") \
    for (int sub = 0; sub < 2; sub++) { \
      f32x4 h1 = MFMA16(B1[sub], A1[m], zf); \
      f32x4 h3 = MFMA16(B3[sub], A3[m], zf); \
      _Pragma("unroll") \
      for (int i = 0; i < 4; i++) { \
        float a = h1[i]; \
        float hv = (a >= 0.f ? a : 0.01f * a) * h3[i]; \
        bf16 hb = __float2bfloat16(hv); \
        hfrag[sub * 4 + i] = *reinterpret_cast<short*>(&hb); \
      } \
    } \
    acc[m] = MFMA16(W2, hfrag, acc[m]); }

__global__ __launch_bounds__(512) void k_fused(
    const float* __restrict__ x, const bf16* __restrict__ bx, int use_bx,
    const bf16* __restrict__ bw1a3,
    const bf16* __restrict__ bw1b, const bf16* __restrict__ bw3b,
    const bf16* __restrict__ bw2apk,
    const int* __restrict__ cnt, const int* __restrict__ tok,
    const float* __restrict__ wl, bf16* __restrict__ accbf)
{
  int item = blockIdx.x;
  int ls = ((item & 7) << 1) | ((item >> 3) & 1);   // expert = XCD (b%8)
  int pt = item >> 4;                               // 0..255
  int n = cnt[ls]; int p0 = pt * 32;
  if (p0 >= n) return;
  int e = ls >> 1;
  int tid = threadIdx.x;
  int w = tid >> 6, l = tid & 63, lm = l & 15, lg = l >> 4;

  __shared__ int toks[32];
  __shared__ __align__(16) bf16 aT[32 * 40];                 // 2.5 KB a1a3 tile
  __shared__ __align__(16) char uni[4352 * 4];               // 17.4 KB union
  float* part = reinterpret_cast<float*>(uni);               // [4][32][33] Phase A
  float* red  = reinterpret_cast<float*>(uni);               // [8][32*17]  Phase B

  const f32x4 zf = {0.f, 0.f, 0.f, 0.f};
  const short8 ZS = {0, 0, 0, 0, 0, 0, 0, 0};

  if (tid < 32) {
    int pos = p0 + tid; if (pos > n - 1) pos = n - 1;
    toks[tid] = tok[ls * T_TOK + pos];
  }
  __syncthreads();

  // ---- Phase A: gathered stage-1, one expert, ILP-4 ----
  {
    int tg = w >> 2, ks = w & 3;            // token-group (2), K-slice (4 x 512)
    const bf16* be = bw1a3 + e * 65536 + ks * 16384 + lg * 8;
    f32x4 a0 = zf, a1 = zf, a2 = zf, a3 = zf;
    if (use_bx) {
      const bf16* xp = bx + (size_t)toks[tg * 16 + lm] * HD + ks * 512 + lg * 8;
#pragma unroll 4
      for (int k2 = 0; k2 < 8; k2++) {
        short8 af0 = *reinterpret_cast<const short8*>(xp + (2 * k2) * 32);
        short8 af1 = *reinterpret_cast<const short8*>(xp + (2 * k2 + 1) * 32);
        short8 b00 = *reinterpret_cast<const short8*>(be + (2 * k2) * 1024 + lm * 32);
        short8 b01 = *reinterpret_cast<const short8*>(be + (2 * k2) * 1024 + (lm + 16) * 32);
        short8 b10 = *reinterpret_cast<const short8*>(be + (2 * k2 + 1) * 1024 + lm * 32);
        short8 b11 = *reinterpret_cast<const short8*>(be + (2 * k2 + 1) * 1024 + (lm + 16) * 32);
        a0 = MFMA16(af0, b00, a0);
        a1 = MFMA16(af0, b01, a1);
        a2 = MFMA16(af1, b10, a2);
        a3 = MFMA16(af1, b11, a3);
      }
    } else {
      const float* xp = x + (size_t)toks[tg * 16 + lm] * HD + ks * 512 + lg * 8;
#pragma unroll 4
      for (int kk2 = 0; kk2 < 16; kk2++) {
        float4 v0 = *reinterpret_cast<const float4*>(xp + kk2 * 32);
        float4 v1 = *reinterpret_cast<const float4*>(xp + kk2 * 32 + 4);
        alignas(16) bf16 tmp[8];
        tmp[0] = __float2bfloat16(v0.x); tmp[1] = __float2bfloat16(v0.y);
        tmp[2] = __float2bfloat16(v0.z); tmp[3] = __float2bfloat16(v0.w);
        tmp[4] = __float2bfloat16(v1.x); tmp[5] = __float2bfloat16(v1.y);
        tmp[6] = __float2bfloat16(v1.z); tmp[7] = __float2bfloat16(v1.w);
        short8 af = *reinterpret_cast<const short8*>(tmp);
        short8 b0 = *reinterpret_cast<const short8*>(be + kk2 * 1024 + lm * 32);
        short8 b1 = *reinterpret_cast<const short8*>(be + kk2 * 1024 + (lm + 16) * 32);
        a0 = MFMA16(af, b0, a0);
        a1 = MFMA16(af, b1, a1);
      }
    }
    a0 += a2; a1 += a3;
    // C: col=lm (rr), row(token-in-group)=lg*4+i
#pragma unroll
    for (int i = 0; i < 4; i++) {
      int row = tg * 16 + lg * 4 + i;
      part[(ks * 32 + row) * 33 + lm]      = a0[i];
      part[(ks * 32 + row) * 33 + 16 + lm] = a1[i];
    }
  }
  __syncthreads();
  { // reduce 4 K-slices -> aT (bf16); 512 threads x 2 elems
    int tokr = tid >> 4, c2 = (tid & 15) * 2;
    float s0 = 0.f, s1 = 0.f;
#pragma unroll
    for (int ks = 0; ks < 4; ks++) {
      s0 += part[(ks * 32 + tokr) * 33 + c2];
      s1 += part[(ks * 32 + tokr) * 33 + c2 + 1];
    }
    aT[tokr * 40 + c2]     = __float2bfloat16(s0);
    aT[tokr * 40 + c2 + 1] = __float2bfloat16(s1);
  }
  __syncthreads();

  // ---- Phase B: F-loop, wave w owns 1024-wide slice ----
  short8 A1[2], A3[2];
#pragma unroll
  for (int m = 0; m < 2; m++) {
    if (lg < 2) {
      A1[m] = *reinterpret_cast<const short8*>(&aT[(m * 16 + lm) * 40 + lg * 8]);
      A3[m] = *reinterpret_cast<const short8*>(&aT[(m * 16 + lm) * 40 + 16 + lg * 8]);
    } else { A1[m] = ZS; A3[m] = ZS; }
  }
  f32x4 acc[2];
  acc[0] = zf; acc[1] = zf;
  int r8 = (lg & 1) * 8;
  const bf16* w1e = bw1b   + (size_t)e * FD * 16;
  const bf16* w3e = bw3b   + (size_t)e * FD * 16;
  const bf16* w2e = bw2apk + (size_t)e * 131072;

  short8 b1A[2], b3A[2], w2A_;
  short8 b1B[2], b3B[2], w2B_;
  LDW(0, b1A, b3A, w2A_);
  for (int ft = 0; ft < 32; ft += 2) {
    LDW(ft + 1, b1B, b3B, w2B_);
    CMP(b1A, b3A, w2A_);
    if (ft + 2 < 32) { LDW(ft + 2, b1A, b3A, w2A_); }
    CMP(b1B, b3B, w2B_);
  }
  // acc[m]: lane holds r = lg*4+i, pair = m*16+lm
#pragma unroll
  for (int m = 0; m < 2; m++)
#pragma unroll
    for (int i = 0; i < 4; i++)
      red[w * 544 + (m * 16 + lm) * 17 + lg * 4 + i] = acc[m][i];
  __syncthreads();
  {
    int p = tid >> 4, rh = tid & 15;       // 32 pairs x 16 r-columns
    int pos = p0 + p;
    if (pos < n) {
      float s = 0.f;
#pragma unroll
      for (int ww = 0; ww < 8; ww++) s += red[ww * 544 + p * 17 + rh];
      float wgt = wl[ls * T_TOK + pos];
      int t = toks[p];
      int sl = ls & 1;
      accbf[((size_t)t * 2 + sl) * 16 + rh] = __float2bfloat16(s * wgt);
    }
  }
}

// ---------------- K4: single-pass dense out: y = acc0@w2B[e0]^T + acc1@w2B[e1]^T -------
// grid: tpt(128) x ht(16); block = 64 tokens x 128 cols; slot0 in K<16, slot1 in K>=16.
__global__ __launch_bounds__(256) void k_out(
    const bf16* __restrict__ accbf, const bf16* __restrict__ bw2b,
    const int* __restrict__ selT, float* __restrict__ out)
{
  int tpt = blockIdx.x >> 4;
  int ht  = blockIdx.x & 15;
  int tid = threadIdx.x, w = tid >> 6, l = tid & 63, lm = l & 15, lg = l >> 4;
  int t0 = tpt * 64;
  int tA = t0 + w * 16 + lm;                 // token carried by this lane's A rows
  int r8 = (lg & 1) * 8;
  int slot = lg >> 1;                        // lg 0,1 -> slot0 (k<16); lg 2,3 -> slot1
  short8 A = *reinterpret_cast<const short8*>(accbf + ((size_t)tA * 2 + slot) * 16 + r8);
  int sel = selT[tA];
  int my_e = (slot == 0) ? (sel & 255) : (sel >> 8);

  const short8 ZS = {0, 0, 0, 0, 0, 0, 0, 0};
  const f32x4 zf = {0.f, 0.f, 0.f, 0.f};
  f32x4 y[2][4];
#pragma unroll
  for (int nt = 0; nt < 2; nt++)
#pragma unroll
    for (int hi = 0; hi < 4; hi++) y[nt][hi] = zf;

#pragma unroll
  for (int e = 0; e < 8; e++) {
    short8 Ae = (my_e == e) ? A : ZS;        // per-lane mask
    const bf16* wbe = bw2b + (size_t)e * HD * 16;
#pragma unroll
    for (int nt = 0; nt < 2; nt++) {
#pragma unroll
      for (int hi = 0; hi < 4; hi++) {
        int h = ht * 128 + nt * 64 + hi * 16 + lm;
        short8 B = *reinterpret_cast<const short8*>(wbe + h * 16 + r8);
        y[nt][hi] = MFMA16(Ae, B, y[nt][hi]);
      }
    }
  }
  // D: row = lg*4+i (token), col = lm (h)
#pragma unroll
  for (int nt = 0; nt < 2; nt++)
#pragma unroll
    for (int hi = 0; hi < 4; hi++)
#pragma unroll
      for (int i = 0; i < 4; i++)
        out[(size_t)(t0 + w * 16 + lg * 4 + i) * HD + ht * 128 + nt * 64 + hi * 16 + lm]
            = y[nt][hi][i];
}

// ---------------- launch ----------------
extern "C" void kernel_launch(void* const* d_in, const int* in_sizes, int n_in,
                              void* d_out, int out_size, void* d_ws, size_t ws_size,
                              hipStream_t stream)
{
  const float* x   = (const float*)d_in[0];
  const float* gw  = (const float*)d_in[1];
  const float* w1A = (const float*)d_in[2];
  const float* w1B = (const float*)d_in[3];
  const float* w2A = (const float*)d_in[4];
  const float* w2B = (const float*)d_in[5];
  const float* w3A = (const float*)d_in[6];
  const float* w3B = (const float*)d_in[7];
  float* out = (float*)d_out;
  float* rw  = out + (size_t)T_TOK * HD;

  char* ws = (char*)d_ws;
  bf16*  bw1a3  = (bf16*)(ws + 0);          //  1 MiB   packed [E][64][32][32]
  bf16*  bw1b   = (bf16*)(ws + 1048576);    //  2 MiB   [E][F][R]
  bf16*  bw3b   = (bf16*)(ws + 3145728);    //  2 MiB
  bf16*  bw2apk = (bf16*)(ws + 5242880);    //  2 MiB   A-frag packed [E][256][64][8]
  bf16*  bw2b   = (bf16*)(ws + 7340032);    //  0.5 MiB [E][H][R]
  bf16*  accbf  = (bf16*)(ws + 16252928);   //  0.5 MiB [T][2][16]
  int*   cnt    = (int*) (ws + 16777216);   //  64 B (padded)
  int*   tok    = (int*) (ws + 16777472);   //  0.5 MiB [16][T]
  float* wl     = (float*)(ws + 17301760);  //  0.5 MiB [16][T]
  int*   selT   = (int*) (ws + 17825792);   //  32 KiB  [T]
  bf16*  bx     = (bf16*)(ws + 18874368);   //  32 MiB  [T][H] bf16 x (optional)
  int use_bx = (ws_size >= (size_t)18874368 + 33554432) ? 1 : 0;

  k_convert<<<dim3(4096), dim3(256), 0, stream>>>(w1A, w1B, w2A, w2B, w3A, w3B,
                                                  bw1a3, bw1b, bw3b, bw2apk, bw2b, cnt);
  k_router <<<dim3(512),  dim3(512), 0, stream>>>(x, gw, rw, cnt, tok, wl, selT, bx, use_bx);
  k_fused  <<<dim3(4096), dim3(512), 0, stream>>>(x, bx, use_bx, bw1a3, bw1b, bw3b, bw2apk,
                                                  cnt, tok, wl, accbf);
  k_out    <<<dim3(2048), dim3(256), 0, stream>>>(accbf, bw2b, selT, out);
}